// Round 17
// baseline (433.304 us; speedup 1.0000x reference)
//
#include <hip/hip_runtime.h>
#include <hip/hip_fp16.h>
#include <math.h>

#define N_NODES 100000
#define N_EDGES 1600000
#define N_ITEMS (N_EDGES + N_NODES)   // edges + self loops
#define F_IN 128
#define HC 64      // H*C (layer-1 output width)
#define NEG 0.2f
#define SCAN_BS 1024
#define SCAN_NB ((N_NODES + SCAN_BS - 1) / SCAN_BS)   // 98
#define MS_BLOCKS 1024

union H2I { __half2 h; int i; };
typedef int v2i __attribute__((ext_vector_type(2)));
typedef int v4i __attribute__((ext_vector_type(4)));
typedef float v4f __attribute__((ext_vector_type(4)));
typedef _Float16 h2 __attribute__((ext_vector_type(2)));

#if __has_builtin(__builtin_amdgcn_fdot2)
__device__ __forceinline__ float DOT2(h2 a, h2 b, float c) {
    return __builtin_amdgcn_fdot2(a, b, c, false);
}
#else
__device__ __forceinline__ float DOT2(h2 a, h2 b, float c) {
    return c + (float)a.x * (float)b.x + (float)a.y * (float)b.y;
}
#endif

// packed fp16 max (header lacks __hmax2 on this ROCm)
__device__ __forceinline__ __half2 hmax2(__half2 a, __half2 b) {
    H2I ua, ub, uc; ua.h = a; ub.h = b;
    asm("v_pk_max_f16 %0, %1, %2" : "=v"(uc.i) : "v"(ua.i), "v"(ub.i));
    return uc.h;
}

// partial sums of edge_attr columns + degree histogram (deg pre-zeroed via memsetAsync)
__global__ void mean_sum_kernel(const float* __restrict__ ea, const int* __restrict__ dst,
                                float* __restrict__ partials, unsigned* __restrict__ deg) {
    __shared__ float sh[4][8];
    int stride = gridDim.x * blockDim.x;
    float acc[8] = {0.f,0.f,0.f,0.f,0.f,0.f,0.f,0.f};
    for (int r = blockIdx.x * blockDim.x + threadIdx.x; r < N_EDGES; r += stride) {
        v4f a = __builtin_nontemporal_load((const v4f*)(ea + (size_t)r * 8));
        v4f b = __builtin_nontemporal_load((const v4f*)(ea + (size_t)r * 8 + 4));
        acc[0] += a.x; acc[1] += a.y; acc[2] += a.z; acc[3] += a.w;
        acc[4] += b.x; acc[5] += b.y; acc[6] += b.z; acc[7] += b.w;
        atomicAdd(&deg[__builtin_nontemporal_load(dst + r)], 1u);
    }
    int wid  = threadIdx.x >> 6;
    int lane = threadIdx.x & 63;
#pragma unroll
    for (int k = 0; k < 8; k++) {
        float v = acc[k];
        for (int off = 32; off; off >>= 1) v += __shfl_down(v, off);
        if (lane == 0) sh[wid][k] = v;
    }
    __syncthreads();
    if (threadIdx.x < 8) {
        float s = sh[0][threadIdx.x] + sh[1][threadIdx.x] + sh[2][threadIdx.x] + sh[3][threadIdx.x];
        partials[blockIdx.x * 8 + threadIdx.x] = s;
    }
}

// inclusive block scan of (deg+1); block 0 additionally reduces partials -> sum8
__global__ void scan1(const unsigned* __restrict__ deg, unsigned* __restrict__ local_inc,
                      unsigned* __restrict__ bsum,
                      const float* __restrict__ partials, float* __restrict__ sum8) {
    if (blockIdx.x == 0 && threadIdx.x < 64) {
        int lane = threadIdx.x;
        int c = lane & 7, g = lane >> 3;
        float s = 0.f;
        for (int b = g; b < MS_BLOCKS; b += 8) s += partials[b * 8 + c];
        s += __shfl_xor(s, 8);
        s += __shfl_xor(s, 16);
        s += __shfl_xor(s, 32);
        if (lane < 8) sum8[lane] = s;
    }
    __shared__ unsigned wsum[16];
    int i = blockIdx.x * SCAN_BS + threadIdx.x;
    int lane = threadIdx.x & 63;
    int wid  = threadIdx.x >> 6;          // 0..15
    unsigned v = (i < N_NODES) ? (deg[i] + 1u) : 0u;   // +1 = self loop
    unsigned sc = v;
#pragma unroll
    for (int off = 1; off < 64; off <<= 1) {
        unsigned t = __shfl_up(sc, off);
        if (lane >= off) sc += t;
    }
    if (lane == 63) wsum[wid] = sc;
    __syncthreads();
    if (threadIdx.x < 16) {
        unsigned w = wsum[threadIdx.x];
#pragma unroll
        for (int off = 1; off < 16; off <<= 1) {
            unsigned t = __shfl_up(w, off);
            if ((int)threadIdx.x >= off) w += t;
        }
        wsum[threadIdx.x] = w;
    }
    __syncthreads();
    unsigned base = wid ? wsum[wid - 1] : 0u;
    sc += base;
    if (i < N_NODES) local_inc[i] = sc;
    if (threadIdx.x == SCAN_BS - 1) bsum[blockIdx.x] = sc;
}

// fused scan2+scan3: re-scan the 98 block sums, then emit next + row_info{start,cnt}
__global__ void scan23(const unsigned* __restrict__ local_inc, const unsigned* __restrict__ deg,
                       const unsigned* __restrict__ bsum,
                       unsigned* __restrict__ next, uint2* __restrict__ row_info) {
    __shared__ unsigned tmp[128];
    int t = threadIdx.x;
    if (t < 128) tmp[t] = (t < SCAN_NB) ? bsum[t] : 0u;
    __syncthreads();
    for (int off = 1; off < 128; off <<= 1) {
        unsigned add = 0u;
        if (t < 128 && t >= off) add = tmp[t - off];
        __syncthreads();
        if (t < 128) tmp[t] += add;
        __syncthreads();
    }
    int i = blockIdx.x * blockDim.x + t;
    if (i >= N_NODES) return;
    int b = i >> 10;                      // i / SCAN_BS
    unsigned base = b ? tmp[b - 1] : 0u;  // exclusive
    unsigned cnt = deg[i] + 1u;
    unsigned v = local_inc[i] - cnt + base;
    next[i] = v;
    row_info[i] = make_uint2(v, cnt);
}

// scatter edges (+ self loops) into destination-sorted 32B AoS records:
// rec32[pos] = {src, see2-bits, ea0..7 fp16}. Nontemporal stores (write-once,
// random positions — keep them out of L2).
__global__ void scatter_kernel(const int* __restrict__ src, const int* __restrict__ dst,
                               const float* __restrict__ ea, const float* __restrict__ sum8,
                               const float* __restrict__ We2,
                               unsigned* __restrict__ next,
                               int* __restrict__ rec32) {
    int item = blockIdx.x * blockDim.x + threadIdx.x;
    if (item >= N_ITEMS) return;
    int s, d;
    v4f a, b;
    if (item < N_EDGES) {
        s = __builtin_nontemporal_load(src + item);
        d = __builtin_nontemporal_load(dst + item);
        a = __builtin_nontemporal_load((const v4f*)(ea + (size_t)item * 8));
        b = __builtin_nontemporal_load((const v4f*)(ea + (size_t)item * 8 + 4));
    } else {
        s = d = item - N_EDGES;
        const float inv = 1.0f / N_EDGES;
        a.x = sum8[0]*inv; a.y = sum8[1]*inv; a.z = sum8[2]*inv; a.w = sum8[3]*inv;
        b.x = sum8[4]*inv; b.y = sum8[5]*inv; b.z = sum8[6]*inv; b.w = sum8[7]*inv;
    }
    float ee2 = a.x*We2[0] + a.y*We2[1] + a.z*We2[2] + a.w*We2[3]
              + b.x*We2[4] + b.y*We2[5] + b.z*We2[6] + b.w*We2[7];
    unsigned pos = atomicAdd(&next[d], 1u);
    H2I e01, e23, e45, e67;
    e01.h = __floats2half2_rn(a.x, a.y);
    e23.h = __floats2half2_rn(a.z, a.w);
    e45.h = __floats2half2_rn(b.x, b.y);
    e67.h = __floats2half2_rn(b.z, b.w);
    int* base = rec32 + (size_t)pos * 8;
    v4i st1; st1.x = s; st1.y = __float_as_int(ee2); st1.z = e01.i; st1.w = e23.i;
    __builtin_nontemporal_store(st1, (v4i*)base);
    v2i st2; st2.x = e45.i; st2.y = e67.i;
    __builtin_nontemporal_store(st2, (v2i*)(base + 4));
}

// xl = x@Wl + bl ; xr = x@Wr + br — fp16 output [node][64].
// W (both tables) staged in LDS as k-paired fp16 (32KB); x tile fp16 (9KB);
// inner loop = v_dot2_f32_f16 (fp16 mul, f32 accumulate). No global W re-reads.
__global__ __launch_bounds__(256) void gemm1_kernel(
        const float* __restrict__ x,
        const float* __restrict__ Wl, const float* __restrict__ bl,
        const float* __restrict__ Wr, const float* __restrict__ br,
        __half* __restrict__ xlh, __half* __restrict__ xrh) {
    __shared__ h2 W16[64][128];           // [kk][combined col] : (W[2kk][c], W[2kk+1][c])
    __shared__ h2 xs16[64][36];           // [kk][node] : (x[n][2kk], x[n][2kk+1]), padded
    int t = threadIdx.x & 31;             // combined col-quad: cols 4t..4t+3 (0..127)
    int g = threadIdx.x >> 5;             // node-quad: nodes 4g..4g+3
    int n0 = blockIdx.x * 32;             // N_NODES = 32*3125 exactly

    // stage W: 64 kk x 16 col-quads per table
    for (int i = threadIdx.x; i < 64 * 16; i += 256) {
        int kk = i >> 4, cq = i & 15;
        float4 w0 = *(const float4*)(Wl + (size_t)(2*kk)   * HC + 4*cq);
        float4 w1 = *(const float4*)(Wl + (size_t)(2*kk+1) * HC + 4*cq);
        h2 p;
        p.x = (_Float16)w0.x; p.y = (_Float16)w1.x; W16[kk][4*cq+0] = p;
        p.x = (_Float16)w0.y; p.y = (_Float16)w1.y; W16[kk][4*cq+1] = p;
        p.x = (_Float16)w0.z; p.y = (_Float16)w1.z; W16[kk][4*cq+2] = p;
        p.x = (_Float16)w0.w; p.y = (_Float16)w1.w; W16[kk][4*cq+3] = p;
        float4 v0 = *(const float4*)(Wr + (size_t)(2*kk)   * HC + 4*cq);
        float4 v1 = *(const float4*)(Wr + (size_t)(2*kk+1) * HC + 4*cq);
        p.x = (_Float16)v0.x; p.y = (_Float16)v1.x; W16[kk][64+4*cq+0] = p;
        p.x = (_Float16)v0.y; p.y = (_Float16)v1.y; W16[kk][64+4*cq+1] = p;
        p.x = (_Float16)v0.z; p.y = (_Float16)v1.z; W16[kk][64+4*cq+2] = p;
        p.x = (_Float16)v0.w; p.y = (_Float16)v1.w; W16[kk][64+4*cq+3] = p;
    }
    // stage x tile (32 nodes), k-paired fp16
    {
        int row = threadIdx.x >> 3;       // 0..31
        int cq  = threadIdx.x & 7;
#pragma unroll
        for (int r = 0; r < 4; r++) {
            int c = cq * 4 + r * 32;      // multiple of 4 -> even
            float4 v = *(const float4*)(x + (size_t)(n0 + row) * F_IN + c);
            h2 p;
            p.x = (_Float16)v.x; p.y = (_Float16)v.y; xs16[c/2][row]     = p;
            p.x = (_Float16)v.z; p.y = (_Float16)v.w; xs16[c/2 + 1][row] = p;
        }
    }
    __syncthreads();

    const float* bsel = (t < 16) ? bl : br;
    int jc = (t < 16) ? 4 * t : 4 * t - HC;
    float4 bias = *(const float4*)(bsel + jc);
    __half* table = (t < 16) ? xlh : xrh;
    int nb = g * 4;

    float4 a0 = bias, a1 = bias, a2 = bias, a3 = bias;
#pragma unroll 4
    for (int kk = 0; kk < 64; kk++) {
        h2 w0 = W16[kk][4*t+0], w1 = W16[kk][4*t+1], w2 = W16[kk][4*t+2], w3 = W16[kk][4*t+3];
        h2 x0 = xs16[kk][nb+0], x1 = xs16[kk][nb+1], x2 = xs16[kk][nb+2], x3 = xs16[kk][nb+3];
        a0.x = DOT2(x0, w0, a0.x); a0.y = DOT2(x0, w1, a0.y); a0.z = DOT2(x0, w2, a0.z); a0.w = DOT2(x0, w3, a0.w);
        a1.x = DOT2(x1, w0, a1.x); a1.y = DOT2(x1, w1, a1.y); a1.z = DOT2(x1, w2, a1.z); a1.w = DOT2(x1, w3, a1.w);
        a2.x = DOT2(x2, w0, a2.x); a2.y = DOT2(x2, w1, a2.y); a2.z = DOT2(x2, w2, a2.z); a2.w = DOT2(x2, w3, a2.w);
        a3.x = DOT2(x3, w0, a3.x); a3.y = DOT2(x3, w1, a3.y); a3.z = DOT2(x3, w2, a3.z); a3.w = DOT2(x3, w3, a3.w);
    }
    float4 arr[4] = {a0, a1, a2, a3};
#pragma unroll
    for (int r = 0; r < 4; r++) {
        H2I u0, u1;
        u0.h = __floats2half2_rn(arr[r].x, arr[r].y);
        u1.h = __floats2half2_rn(arr[r].z, arr[r].w);
        *(int2*)(table + (size_t)(n0 + nb + r) * HC + jc) = make_int2(u0.i, u1.i);
    }
}

// packed-fp16 edge update (no-max softmax; self loop guarantees den > 0)
__device__ __forceinline__ void edge_update_h(const __half2* __restrict__ weA,
                                              const __half2* __restrict__ weB,
                                              __half2 attA, __half2 attB,
                                              __half2 xr2a, __half2 xr2b,
                                              bool valid, v4i L1, v2i L2, v2i xp,
                                              float& den, float4& acc) {
    H2I ea01, ea23, ea45, ea67, xl01, xl23;
    ea01.i = L1.z; ea23.i = L1.w; ea45.i = L2.x; ea67.i = L2.y;
    xl01.i = xp.x; xl23.i = xp.y;
    __half2 va = __hadd2(xl01.h, xr2a);
    __half2 vb = __hadd2(xl23.h, xr2b);
    __half2 e;
    e = __low2half2(ea01.h);  va = __hfma2(e, weA[0], va); vb = __hfma2(e, weB[0], vb);
    e = __high2half2(ea01.h); va = __hfma2(e, weA[1], va); vb = __hfma2(e, weB[1], vb);
    e = __low2half2(ea23.h);  va = __hfma2(e, weA[2], va); vb = __hfma2(e, weB[2], vb);
    e = __high2half2(ea23.h); va = __hfma2(e, weA[3], va); vb = __hfma2(e, weB[3], vb);
    e = __low2half2(ea45.h);  va = __hfma2(e, weA[4], va); vb = __hfma2(e, weB[4], vb);
    e = __high2half2(ea45.h); va = __hfma2(e, weA[5], va); vb = __hfma2(e, weB[5], vb);
    e = __low2half2(ea67.h);  va = __hfma2(e, weA[6], va); vb = __hfma2(e, weB[6], vb);
    e = __high2half2(ea67.h); va = __hfma2(e, weA[7], va); vb = __hfma2(e, weB[7], vb);
    const __half2 k02 = __float2half2_rn(NEG);
    va = hmax2(va, __hmul2(va, k02));        // leakyrelu
    vb = hmax2(vb, __hmul2(vb, k02));
    __half2 pd = __hfma2(vb, attB, __hmul2(va, attA));
    float2 pf = __half22float2(pd);
    float prod = pf.x + pf.y;
    prod += __shfl_xor(prod, 1);
    prod += __shfl_xor(prod, 2);             // per-head logit in each 4-lane cluster
    float p = valid ? __expf(prod) : 0.f;
    float2 xa = __half22float2(xl01.h), xb = __half22float2(xl23.h);
    den   += p;
    acc.x += p * xa.x;
    acc.y += p * xa.y;
    acc.z += p * xb.x;
    acc.w += p * xb.y;
}

// fused layer-1: one wave per node, 8 edges/iter as two streams, depth-1 prefetch.
// fp16 packed math, f32 softmax accumulation, no-max. Epilogue: bias+ELU+layer-2 proj.
__global__ void gat1_kernel(const uint2* __restrict__ row_info,
                            const int* __restrict__ rec32,
                            const float* __restrict__ We1, const float* __restrict__ att1,
                            const float* __restrict__ b1,
                            const __half* __restrict__ xlh, const __half* __restrict__ xrh,
                            const float* __restrict__ Wl2, const float* __restrict__ bl2,
                            const float* __restrict__ Wr2, const float* __restrict__ br2,
                            float* __restrict__ xl2, float* __restrict__ xr2) {
    int node = blockIdx.x * (blockDim.x >> 6) + (threadIdx.x >> 6);
    int lane = threadIdx.x & 63;
    if (node >= N_NODES) return;
    int g  = lane >> 4;          // edge sub-stream 0..3
    int cl = lane & 15;          // channel-slot: channels 4cl..4cl+3
    uint2 ri = row_info[node];
    unsigned start = ri.x;
    unsigned cnt   = ri.y;
    unsigned cm1   = cnt - 1u;

    __half2 weA[8], weB[8];
#pragma unroll
    for (int k = 0; k < 8; k++) {
        float4 w = *(const float4*)(We1 + k * HC + 4 * cl);
        weA[k] = __floats2half2_rn(w.x, w.y);
        weB[k] = __floats2half2_rn(w.z, w.w);
    }
    float4 at = *(const float4*)(att1 + 4 * cl);
    __half2 attA = __floats2half2_rn(at.x, at.y);
    __half2 attB = __floats2half2_rn(at.z, at.w);
    v2i xrp = *(const v2i*)(xrh + (size_t)node * HC + 4 * cl);
    H2I xru0, xru1; xru0.i = xrp.x; xru1.i = xrp.y;
    __half2 xr2a = xru0.h, xr2b = xru1.h;

    float denA = 0.f, denB = 0.f;
    float4 accA = make_float4(0.f,0.f,0.f,0.f), accB = make_float4(0.f,0.f,0.f,0.f);

#define IDXA(J) (start + min((J) + (unsigned)g, cm1))
#define IDXB(J) (start + min((J) + 4u + (unsigned)g, cm1))
    // prologue: depth-1 prefetch, two streams
    unsigned iA = IDXA(0u), iB = IDXB(0u);
    v4i L1A = __builtin_nontemporal_load((const v4i*)(rec32 + (size_t)iA * 8));
    v4i L1B = __builtin_nontemporal_load((const v4i*)(rec32 + (size_t)iB * 8));
    v2i L2A = __builtin_nontemporal_load((const v2i*)(rec32 + (size_t)iA * 8 + 4));
    v2i L2B = __builtin_nontemporal_load((const v2i*)(rec32 + (size_t)iB * 8 + 4));
    v2i xpA = *(const v2i*)(xlh + (size_t)L1A.x * HC + 4 * cl);
    v2i xpB = *(const v2i*)(xlh + (size_t)L1B.x * HC + 4 * cl);

    for (unsigned j = 0; j < cnt; j += 8) {
        v4i c1A = L1A, c1B = L1B;
        v2i c2A = L2A, c2B = L2B, cxA = xpA, cxB = xpB;
        bool vA = (j + g) < cnt, vB = (j + 4 + g) < cnt;
        if (j + 8 < cnt) {
            iA = IDXA(j + 8); iB = IDXB(j + 8);
            L1A = __builtin_nontemporal_load((const v4i*)(rec32 + (size_t)iA * 8));
            L1B = __builtin_nontemporal_load((const v4i*)(rec32 + (size_t)iB * 8));
            L2A = __builtin_nontemporal_load((const v2i*)(rec32 + (size_t)iA * 8 + 4));
            L2B = __builtin_nontemporal_load((const v2i*)(rec32 + (size_t)iB * 8 + 4));
            xpA = *(const v2i*)(xlh + (size_t)L1A.x * HC + 4 * cl);
            xpB = *(const v2i*)(xlh + (size_t)L1B.x * HC + 4 * cl);
        }
        edge_update_h(weA, weB, attA, attB, xr2a, xr2b, vA, c1A, c2A, cxA, denA, accA);
        edge_update_h(weA, weB, attA, attB, xr2a, xr2b, vB, c1B, c2B, cxB, denB, accB);
    }
#undef IDXA
#undef IDXB

    float den = denA + denB;
    float4 acc;
    acc.x = accA.x + accB.x;
    acc.y = accA.y + accB.y;
    acc.z = accA.z + accB.z;
    acc.w = accA.w + accB.w;

    // merge the 4 g-streams (lanes differing in bits 4,5) — plain sums
    den   += __shfl_xor(den, 16);   den   += __shfl_xor(den, 32);
    acc.x += __shfl_xor(acc.x, 16); acc.x += __shfl_xor(acc.x, 32);
    acc.y += __shfl_xor(acc.y, 16); acc.y += __shfl_xor(acc.y, 32);
    acc.z += __shfl_xor(acc.z, 16); acc.z += __shfl_xor(acc.z, 32);
    acc.w += __shfl_xor(acc.w, 16); acc.w += __shfl_xor(acc.w, 32);

    float4 b1v  = *(const float4*)(b1 + 4 * cl);
    float4 wl2v = *(const float4*)(Wl2 + 4 * cl);
    float4 wr2v = *(const float4*)(Wr2 + 4 * cl);
    float inv_den = 1.f / den;
    float4 o;
    o.x = acc.x * inv_den + b1v.x;
    o.y = acc.y * inv_den + b1v.y;
    o.z = acc.z * inv_den + b1v.z;
    o.w = acc.w * inv_den + b1v.w;
    o.x = o.x > 0.f ? o.x : __expf(o.x) - 1.f;   // ELU
    o.y = o.y > 0.f ? o.y : __expf(o.y) - 1.f;
    o.z = o.z > 0.f ? o.z : __expf(o.z) - 1.f;
    o.w = o.w > 0.f ? o.w : __expf(o.w) - 1.f;
    float sl = o.x*wl2v.x + o.y*wl2v.y + o.z*wl2v.z + o.w*wl2v.w;
    float sr = o.x*wr2v.x + o.y*wr2v.y + o.z*wr2v.z + o.w*wr2v.w;
#pragma unroll
    for (int off = 1; off <= 8; off <<= 1) {
        sl += __shfl_xor(sl, off);
        sr += __shfl_xor(sr, off);
    }
    if (lane == 0) {
        xl2[node] = sl + bl2[0];
        xr2[node] = sr + br2[0];
    }
}

// fused layer-2: 16 lanes per node (4 nodes/wave), no-max softmax.
__global__ __launch_bounds__(256) void gat2_kernel(
        const uint2* __restrict__ row_info,
        const int* __restrict__ rec32, const float* __restrict__ att2,
        const float* __restrict__ xl2, const float* __restrict__ xr2,
        const float* __restrict__ b2, float* __restrict__ out) {
    int wave = threadIdx.x >> 6;
    int lane = threadIdx.x & 63;
    int sub  = lane >> 4;                 // node within wave
    int l    = lane & 15;
    int node = (blockIdx.x * 4 + wave) * 4 + sub;   // grid 6250 * 16 = 100000 exact
    uint2 ri = row_info[node];
    unsigned start = ri.x;
    unsigned cnt   = ri.y;
    float xrv = xr2[node];
    float a2  = att2[0];
    float den = 0.f, num = 0.f;
    for (unsigned idx = (unsigned)l; idx < cnt; idx += 16) {
        v2i r = __builtin_nontemporal_load((const v2i*)(rec32 + (size_t)(start + idx) * 8));
        float ee = __int_as_float(r.y);
        float xv = xl2[r.x];
        float v = xv + xrv + ee;
        v = fmaxf(v, NEG * v);
        float p = __expf(a2 * v);
        den += p;
        num += p * xv;
    }
#pragma unroll
    for (int off = 1; off <= 8; off <<= 1) {
        den += __shfl_xor(den, off);
        num += __shfl_xor(num, off);
    }
    if (l == 0) __builtin_nontemporal_store(num / den + b2[0], out + node);
}

extern "C" void kernel_launch(void* const* d_in, const int* in_sizes, int n_in,
                              void* d_out, int out_size, void* d_ws, size_t ws_size,
                              hipStream_t stream) {
    const float* x    = (const float*)d_in[0];
    const int*   ei   = (const int*)d_in[1];
    const float* ea   = (const float*)d_in[2];
    const float* Wl1  = (const float*)d_in[3];
    const float* bl1  = (const float*)d_in[4];
    const float* Wr1  = (const float*)d_in[5];
    const float* br1  = (const float*)d_in[6];
    const float* We1  = (const float*)d_in[7];
    const float* att1 = (const float*)d_in[8];
    const float* b1   = (const float*)d_in[9];
    const float* Wl2  = (const float*)d_in[10];
    const float* bl2  = (const float*)d_in[11];
    const float* Wr2  = (const float*)d_in[12];
    const float* br2  = (const float*)d_in[13];
    const float* We2  = (const float*)d_in[14];
    const float* att2 = (const float*)d_in[15];
    const float* b2   = (const float*)d_in[16];

    const int* src = ei;              // edge_index row 0
    const int* dst = ei + N_EDGES;    // edge_index row 1

    float* W = (float*)d_ws;
    size_t o = 0;
    float*    sum8      = W + o;               o += 8;
    float*    partials  = W + o;               o += MS_BLOCKS * 8;
    unsigned* deg       = (unsigned*)(W + o);  o += N_NODES;
    unsigned* local_inc = (unsigned*)(W + o);  o += N_NODES;
    unsigned* bsum      = (unsigned*)(W + o);  o += 128;
    unsigned* next      = (unsigned*)(W + o);  o += N_NODES;
    uint2*    row_info  = (uint2*)(W + o);     o += (size_t)N_NODES * 2;
    o = (o + 7) & ~(size_t)7;                  // 32B align
    int*      rec32     = (int*)(W + o);       o += (size_t)N_ITEMS * 8;      // 32B AoS
    __half*   xlh       = (__half*)(W + o);    o += (size_t)N_NODES * (HC/2); // fp16 xl
    __half*   xrh       = (__half*)(W + o);    o += (size_t)N_NODES * (HC/2); // fp16 xr
    float*    xl2       = W + o;               o += N_NODES;
    float*    xr2       = W + o;               o += N_NODES;

    hipMemsetAsync(deg, 0, (size_t)N_NODES * sizeof(unsigned), stream);
    mean_sum_kernel<<<MS_BLOCKS, 256, 0, stream>>>(ea, dst, partials, deg);
    scan1<<<SCAN_NB, SCAN_BS, 0, stream>>>(deg, local_inc, bsum, partials, sum8);
    scan23<<<(N_NODES + 255) / 256, 256, 0, stream>>>(local_inc, deg, bsum, next, row_info);
    scatter_kernel<<<(N_ITEMS + 255) / 256, 256, 0, stream>>>(
        src, dst, ea, sum8, We2, next, rec32);
    gemm1_kernel<<<N_NODES / 32, 256, 0, stream>>>(x, Wl1, bl1, Wr1, br1, xlh, xrh);
    gat1_kernel<<<(N_NODES + 3) / 4, 256, 0, stream>>>(
        row_info, rec32, We1, att1, b1, xlh, xrh,
        Wl2, bl2, Wr2, br2, xl2, xr2);
    gat2_kernel<<<N_NODES / 16, 256, 0, stream>>>(
        row_info, rec32, att2, xl2, xr2, b2, (float*)d_out);
}

// Round 18
// 391.805 us; speedup vs baseline: 1.1059x; 1.1059x over previous
//
#include <hip/hip_runtime.h>
#include <hip/hip_fp16.h>
#include <math.h>

#define N_NODES 100000
#define N_EDGES 1600000
#define N_ITEMS (N_EDGES + N_NODES)   // edges + self loops
#define F_IN 128
#define HC 64      // H*C (layer-1 output width)
#define NEG 0.2f
#define SCAN_BS 1024
#define SCAN_NB ((N_NODES + SCAN_BS - 1) / SCAN_BS)   // 98
#define MS_BLOCKS 1024

union H2I { __half2 h; int i; };
typedef int v2i __attribute__((ext_vector_type(2)));
typedef int v4i __attribute__((ext_vector_type(4)));
typedef _Float16 h2 __attribute__((ext_vector_type(2)));

#if __has_builtin(__builtin_amdgcn_fdot2)
__device__ __forceinline__ float DOT2(h2 a, h2 b, float c) {
    return __builtin_amdgcn_fdot2(a, b, c, false);
}
#else
__device__ __forceinline__ float DOT2(h2 a, h2 b, float c) {
    return c + (float)a.x * (float)b.x + (float)a.y * (float)b.y;
}
#endif

// packed fp16 max (header lacks __hmax2 on this ROCm)
__device__ __forceinline__ __half2 hmax2(__half2 a, __half2 b) {
    H2I ua, ub, uc; ua.h = a; ub.h = b;
    asm("v_pk_max_f16 %0, %1, %2" : "=v"(uc.i) : "v"(ua.i), "v"(ub.i));
    return uc.h;
}

// partial sums of edge_attr columns + degree histogram (deg pre-zeroed via memsetAsync)
__global__ void mean_sum_kernel(const float* __restrict__ ea, const int* __restrict__ dst,
                                float* __restrict__ partials, unsigned* __restrict__ deg) {
    __shared__ float sh[4][8];
    int stride = gridDim.x * blockDim.x;
    float acc[8] = {0.f,0.f,0.f,0.f,0.f,0.f,0.f,0.f};
    for (int r = blockIdx.x * blockDim.x + threadIdx.x; r < N_EDGES; r += stride) {
        const float4* p = (const float4*)(ea + (size_t)r * 8);
        float4 a = p[0], b = p[1];
        acc[0] += a.x; acc[1] += a.y; acc[2] += a.z; acc[3] += a.w;
        acc[4] += b.x; acc[5] += b.y; acc[6] += b.z; acc[7] += b.w;
        atomicAdd(&deg[dst[r]], 1u);
    }
    int wid  = threadIdx.x >> 6;
    int lane = threadIdx.x & 63;
#pragma unroll
    for (int k = 0; k < 8; k++) {
        float v = acc[k];
        for (int off = 32; off; off >>= 1) v += __shfl_down(v, off);
        if (lane == 0) sh[wid][k] = v;
    }
    __syncthreads();
    if (threadIdx.x < 8) {
        float s = sh[0][threadIdx.x] + sh[1][threadIdx.x] + sh[2][threadIdx.x] + sh[3][threadIdx.x];
        partials[blockIdx.x * 8 + threadIdx.x] = s;
    }
}

// inclusive block scan of (deg+1); block 0 additionally reduces partials -> sum8
__global__ void scan1(const unsigned* __restrict__ deg, unsigned* __restrict__ local_inc,
                      unsigned* __restrict__ bsum,
                      const float* __restrict__ partials, float* __restrict__ sum8) {
    if (blockIdx.x == 0 && threadIdx.x < 64) {
        int lane = threadIdx.x;
        int c = lane & 7, g = lane >> 3;
        float s = 0.f;
        for (int b = g; b < MS_BLOCKS; b += 8) s += partials[b * 8 + c];
        s += __shfl_xor(s, 8);
        s += __shfl_xor(s, 16);
        s += __shfl_xor(s, 32);
        if (lane < 8) sum8[lane] = s;
    }
    __shared__ unsigned wsum[16];
    int i = blockIdx.x * SCAN_BS + threadIdx.x;
    int lane = threadIdx.x & 63;
    int wid  = threadIdx.x >> 6;          // 0..15
    unsigned v = (i < N_NODES) ? (deg[i] + 1u) : 0u;   // +1 = self loop
    unsigned sc = v;
#pragma unroll
    for (int off = 1; off < 64; off <<= 1) {
        unsigned t = __shfl_up(sc, off);
        if (lane >= off) sc += t;
    }
    if (lane == 63) wsum[wid] = sc;
    __syncthreads();
    if (threadIdx.x < 16) {
        unsigned w = wsum[threadIdx.x];
#pragma unroll
        for (int off = 1; off < 16; off <<= 1) {
            unsigned t = __shfl_up(w, off);
            if ((int)threadIdx.x >= off) w += t;
        }
        wsum[threadIdx.x] = w;
    }
    __syncthreads();
    unsigned base = wid ? wsum[wid - 1] : 0u;
    sc += base;
    if (i < N_NODES) local_inc[i] = sc;
    if (threadIdx.x == SCAN_BS - 1) bsum[blockIdx.x] = sc;
}

// fused scan2+scan3: re-scan the 98 block sums, then emit next + row_info{start,cnt}
__global__ void scan23(const unsigned* __restrict__ local_inc, const unsigned* __restrict__ deg,
                       const unsigned* __restrict__ bsum,
                       unsigned* __restrict__ next, uint2* __restrict__ row_info) {
    __shared__ unsigned tmp[128];
    int t = threadIdx.x;
    if (t < 128) tmp[t] = (t < SCAN_NB) ? bsum[t] : 0u;
    __syncthreads();
    for (int off = 1; off < 128; off <<= 1) {
        unsigned add = 0u;
        if (t < 128 && t >= off) add = tmp[t - off];
        __syncthreads();
        if (t < 128) tmp[t] += add;
        __syncthreads();
    }
    int i = blockIdx.x * blockDim.x + t;
    if (i >= N_NODES) return;
    int b = i >> 10;                      // i / SCAN_BS
    unsigned base = b ? tmp[b - 1] : 0u;  // exclusive
    unsigned cnt = deg[i] + 1u;
    unsigned v = local_inc[i] - cnt + base;
    next[i] = v;
    row_info[i] = make_uint2(v, cnt);
}

// scatter edges (+ self loops) into destination-sorted 32B AoS records:
// rec32[pos] = {src, see2-bits, ea0..7 fp16} — one cache line per edge.
__global__ void scatter_kernel(const int* __restrict__ src, const int* __restrict__ dst,
                               const float* __restrict__ ea, const float* __restrict__ sum8,
                               const float* __restrict__ We2,
                               unsigned* __restrict__ next,
                               int* __restrict__ rec32) {
    int item = blockIdx.x * blockDim.x + threadIdx.x;
    if (item >= N_ITEMS) return;
    int s, d;
    float4 a, b;
    if (item < N_EDGES) {
        s = src[item]; d = dst[item];
        const float4* p = (const float4*)(ea + (size_t)item * 8);
        a = p[0]; b = p[1];
    } else {
        s = d = item - N_EDGES;
        const float inv = 1.0f / N_EDGES;
        a = make_float4(sum8[0]*inv, sum8[1]*inv, sum8[2]*inv, sum8[3]*inv);
        b = make_float4(sum8[4]*inv, sum8[5]*inv, sum8[6]*inv, sum8[7]*inv);
    }
    float ee2 = a.x*We2[0] + a.y*We2[1] + a.z*We2[2] + a.w*We2[3]
              + b.x*We2[4] + b.y*We2[5] + b.z*We2[6] + b.w*We2[7];
    unsigned pos = atomicAdd(&next[d], 1u);
    H2I e01, e23, e45, e67;
    e01.h = __floats2half2_rn(a.x, a.y);
    e23.h = __floats2half2_rn(a.z, a.w);
    e45.h = __floats2half2_rn(b.x, b.y);
    e67.h = __floats2half2_rn(b.z, b.w);
    int* base = rec32 + (size_t)pos * 8;
    v4i st1; st1.x = s; st1.y = __float_as_int(ee2); st1.z = e01.i; st1.w = e23.i;
    *(v4i*)base = st1;
    v2i st2; st2.x = e45.i; st2.y = e67.i;
    *(v2i*)(base + 4) = st2;
}

// xl = x@Wl + bl ; xr = x@Wr + br — fp16 output [node][64].
// W (both tables) staged in LDS as k-paired fp16 (32KB); x tile fp16 (9KB);
// inner loop = v_dot2_f32_f16 (fp16 mul, f32 accumulate). No global W re-reads.
__global__ __launch_bounds__(256) void gemm1_kernel(
        const float* __restrict__ x,
        const float* __restrict__ Wl, const float* __restrict__ bl,
        const float* __restrict__ Wr, const float* __restrict__ br,
        __half* __restrict__ xlh, __half* __restrict__ xrh) {
    __shared__ h2 W16[64][128];           // [kk][combined col] : (W[2kk][c], W[2kk+1][c])
    __shared__ h2 xs16[64][36];           // [kk][node] : (x[n][2kk], x[n][2kk+1]), padded
    int t = threadIdx.x & 31;             // combined col-quad: cols 4t..4t+3 (0..127)
    int g = threadIdx.x >> 5;             // node-quad: nodes 4g..4g+3
    int n0 = blockIdx.x * 32;             // N_NODES = 32*3125 exactly

    // stage W: 64 kk x 16 col-quads per table
    for (int i = threadIdx.x; i < 64 * 16; i += 256) {
        int kk = i >> 4, cq = i & 15;
        float4 w0 = *(const float4*)(Wl + (size_t)(2*kk)   * HC + 4*cq);
        float4 w1 = *(const float4*)(Wl + (size_t)(2*kk+1) * HC + 4*cq);
        h2 p;
        p.x = (_Float16)w0.x; p.y = (_Float16)w1.x; W16[kk][4*cq+0] = p;
        p.x = (_Float16)w0.y; p.y = (_Float16)w1.y; W16[kk][4*cq+1] = p;
        p.x = (_Float16)w0.z; p.y = (_Float16)w1.z; W16[kk][4*cq+2] = p;
        p.x = (_Float16)w0.w; p.y = (_Float16)w1.w; W16[kk][4*cq+3] = p;
        float4 v0 = *(const float4*)(Wr + (size_t)(2*kk)   * HC + 4*cq);
        float4 v1 = *(const float4*)(Wr + (size_t)(2*kk+1) * HC + 4*cq);
        p.x = (_Float16)v0.x; p.y = (_Float16)v1.x; W16[kk][64+4*cq+0] = p;
        p.x = (_Float16)v0.y; p.y = (_Float16)v1.y; W16[kk][64+4*cq+1] = p;
        p.x = (_Float16)v0.z; p.y = (_Float16)v1.z; W16[kk][64+4*cq+2] = p;
        p.x = (_Float16)v0.w; p.y = (_Float16)v1.w; W16[kk][64+4*cq+3] = p;
    }
    // stage x tile (32 nodes), k-paired fp16
    {
        int row = threadIdx.x >> 3;       // 0..31
        int cq  = threadIdx.x & 7;
#pragma unroll
        for (int r = 0; r < 4; r++) {
            int c = cq * 4 + r * 32;      // multiple of 4 -> even
            float4 v = *(const float4*)(x + (size_t)(n0 + row) * F_IN + c);
            h2 p;
            p.x = (_Float16)v.x; p.y = (_Float16)v.y; xs16[c/2][row]     = p;
            p.x = (_Float16)v.z; p.y = (_Float16)v.w; xs16[c/2 + 1][row] = p;
        }
    }
    __syncthreads();

    const float* bsel = (t < 16) ? bl : br;
    int jc = (t < 16) ? 4 * t : 4 * t - HC;
    float4 bias = *(const float4*)(bsel + jc);
    __half* table = (t < 16) ? xlh : xrh;
    int nb = g * 4;

    float4 a0 = bias, a1 = bias, a2 = bias, a3 = bias;
#pragma unroll 4
    for (int kk = 0; kk < 64; kk++) {
        h2 w0 = W16[kk][4*t+0], w1 = W16[kk][4*t+1], w2 = W16[kk][4*t+2], w3 = W16[kk][4*t+3];
        h2 x0 = xs16[kk][nb+0], x1 = xs16[kk][nb+1], x2 = xs16[kk][nb+2], x3 = xs16[kk][nb+3];
        a0.x = DOT2(x0, w0, a0.x); a0.y = DOT2(x0, w1, a0.y); a0.z = DOT2(x0, w2, a0.z); a0.w = DOT2(x0, w3, a0.w);
        a1.x = DOT2(x1, w0, a1.x); a1.y = DOT2(x1, w1, a1.y); a1.z = DOT2(x1, w2, a1.z); a1.w = DOT2(x1, w3, a1.w);
        a2.x = DOT2(x2, w0, a2.x); a2.y = DOT2(x2, w1, a2.y); a2.z = DOT2(x2, w2, a2.z); a2.w = DOT2(x2, w3, a2.w);
        a3.x = DOT2(x3, w0, a3.x); a3.y = DOT2(x3, w1, a3.y); a3.z = DOT2(x3, w2, a3.z); a3.w = DOT2(x3, w3, a3.w);
    }
    float4 arr[4] = {a0, a1, a2, a3};
#pragma unroll
    for (int r = 0; r < 4; r++) {
        H2I u0, u1;
        u0.h = __floats2half2_rn(arr[r].x, arr[r].y);
        u1.h = __floats2half2_rn(arr[r].z, arr[r].w);
        *(int2*)(table + (size_t)(n0 + nb + r) * HC + jc) = make_int2(u0.i, u1.i);
    }
}

// packed-fp16 edge update (no-max softmax; self loop guarantees den > 0)
__device__ __forceinline__ void edge_update_h(const __half2* __restrict__ weA,
                                              const __half2* __restrict__ weB,
                                              __half2 attA, __half2 attB,
                                              __half2 xr2a, __half2 xr2b,
                                              bool valid, v4i L1, v2i L2, v2i xp,
                                              float& den, float4& acc) {
    H2I ea01, ea23, ea45, ea67, xl01, xl23;
    ea01.i = L1.z; ea23.i = L1.w; ea45.i = L2.x; ea67.i = L2.y;
    xl01.i = xp.x; xl23.i = xp.y;
    __half2 va = __hadd2(xl01.h, xr2a);
    __half2 vb = __hadd2(xl23.h, xr2b);
    __half2 e;
    e = __low2half2(ea01.h);  va = __hfma2(e, weA[0], va); vb = __hfma2(e, weB[0], vb);
    e = __high2half2(ea01.h); va = __hfma2(e, weA[1], va); vb = __hfma2(e, weB[1], vb);
    e = __low2half2(ea23.h);  va = __hfma2(e, weA[2], va); vb = __hfma2(e, weB[2], vb);
    e = __high2half2(ea23.h); va = __hfma2(e, weA[3], va); vb = __hfma2(e, weB[3], vb);
    e = __low2half2(ea45.h);  va = __hfma2(e, weA[4], va); vb = __hfma2(e, weB[4], vb);
    e = __high2half2(ea45.h); va = __hfma2(e, weA[5], va); vb = __hfma2(e, weB[5], vb);
    e = __low2half2(ea67.h);  va = __hfma2(e, weA[6], va); vb = __hfma2(e, weB[6], vb);
    e = __high2half2(ea67.h); va = __hfma2(e, weA[7], va); vb = __hfma2(e, weB[7], vb);
    const __half2 k02 = __float2half2_rn(NEG);
    va = hmax2(va, __hmul2(va, k02));        // leakyrelu
    vb = hmax2(vb, __hmul2(vb, k02));
    __half2 pd = __hfma2(vb, attB, __hmul2(va, attA));
    float2 pf = __half22float2(pd);
    float prod = pf.x + pf.y;
    prod += __shfl_xor(prod, 1);
    prod += __shfl_xor(prod, 2);             // per-head logit in each 4-lane cluster
    float p = valid ? __expf(prod) : 0.f;
    float2 xa = __half22float2(xl01.h), xb = __half22float2(xl23.h);
    den   += p;
    acc.x += p * xa.x;
    acc.y += p * xa.y;
    acc.z += p * xb.x;
    acc.w += p * xb.y;
}

// fused layer-1: one wave per node, 8 edges/iter as two streams, depth-1 prefetch.
// fp16 packed math, f32 softmax accumulation, no-max. Epilogue: bias+ELU+layer-2 proj.
__global__ void gat1_kernel(const uint2* __restrict__ row_info,
                            const int* __restrict__ rec32,
                            const float* __restrict__ We1, const float* __restrict__ att1,
                            const float* __restrict__ b1,
                            const __half* __restrict__ xlh, const __half* __restrict__ xrh,
                            const float* __restrict__ Wl2, const float* __restrict__ bl2,
                            const float* __restrict__ Wr2, const float* __restrict__ br2,
                            float* __restrict__ xl2, float* __restrict__ xr2) {
    int node = blockIdx.x * (blockDim.x >> 6) + (threadIdx.x >> 6);
    int lane = threadIdx.x & 63;
    if (node >= N_NODES) return;
    int g  = lane >> 4;          // edge sub-stream 0..3
    int cl = lane & 15;          // channel-slot: channels 4cl..4cl+3
    uint2 ri = row_info[node];
    unsigned start = ri.x;
    unsigned cnt   = ri.y;
    unsigned cm1   = cnt - 1u;

    __half2 weA[8], weB[8];
#pragma unroll
    for (int k = 0; k < 8; k++) {
        float4 w = *(const float4*)(We1 + k * HC + 4 * cl);
        weA[k] = __floats2half2_rn(w.x, w.y);
        weB[k] = __floats2half2_rn(w.z, w.w);
    }
    float4 at = *(const float4*)(att1 + 4 * cl);
    __half2 attA = __floats2half2_rn(at.x, at.y);
    __half2 attB = __floats2half2_rn(at.z, at.w);
    v2i xrp = *(const v2i*)(xrh + (size_t)node * HC + 4 * cl);
    H2I xru0, xru1; xru0.i = xrp.x; xru1.i = xrp.y;
    __half2 xr2a = xru0.h, xr2b = xru1.h;

    float denA = 0.f, denB = 0.f;
    float4 accA = make_float4(0.f,0.f,0.f,0.f), accB = make_float4(0.f,0.f,0.f,0.f);

#define IDXA(J) (start + min((J) + (unsigned)g, cm1))
#define IDXB(J) (start + min((J) + 4u + (unsigned)g, cm1))
    // prologue: depth-1 prefetch, two streams
    unsigned iA = IDXA(0u), iB = IDXB(0u);
    v4i L1A = __builtin_nontemporal_load((const v4i*)(rec32 + (size_t)iA * 8));
    v4i L1B = __builtin_nontemporal_load((const v4i*)(rec32 + (size_t)iB * 8));
    v2i L2A = __builtin_nontemporal_load((const v2i*)(rec32 + (size_t)iA * 8 + 4));
    v2i L2B = __builtin_nontemporal_load((const v2i*)(rec32 + (size_t)iB * 8 + 4));
    v2i xpA = *(const v2i*)(xlh + (size_t)L1A.x * HC + 4 * cl);
    v2i xpB = *(const v2i*)(xlh + (size_t)L1B.x * HC + 4 * cl);

    for (unsigned j = 0; j < cnt; j += 8) {
        v4i c1A = L1A, c1B = L1B;
        v2i c2A = L2A, c2B = L2B, cxA = xpA, cxB = xpB;
        bool vA = (j + g) < cnt, vB = (j + 4 + g) < cnt;
        if (j + 8 < cnt) {
            iA = IDXA(j + 8); iB = IDXB(j + 8);
            L1A = __builtin_nontemporal_load((const v4i*)(rec32 + (size_t)iA * 8));
            L1B = __builtin_nontemporal_load((const v4i*)(rec32 + (size_t)iB * 8));
            L2A = __builtin_nontemporal_load((const v2i*)(rec32 + (size_t)iA * 8 + 4));
            L2B = __builtin_nontemporal_load((const v2i*)(rec32 + (size_t)iB * 8 + 4));
            xpA = *(const v2i*)(xlh + (size_t)L1A.x * HC + 4 * cl);
            xpB = *(const v2i*)(xlh + (size_t)L1B.x * HC + 4 * cl);
        }
        edge_update_h(weA, weB, attA, attB, xr2a, xr2b, vA, c1A, c2A, cxA, denA, accA);
        edge_update_h(weA, weB, attA, attB, xr2a, xr2b, vB, c1B, c2B, cxB, denB, accB);
    }
#undef IDXA
#undef IDXB

    float den = denA + denB;
    float4 acc;
    acc.x = accA.x + accB.x;
    acc.y = accA.y + accB.y;
    acc.z = accA.z + accB.z;
    acc.w = accA.w + accB.w;

    // merge the 4 g-streams (lanes differing in bits 4,5) — plain sums
    den   += __shfl_xor(den, 16);   den   += __shfl_xor(den, 32);
    acc.x += __shfl_xor(acc.x, 16); acc.x += __shfl_xor(acc.x, 32);
    acc.y += __shfl_xor(acc.y, 16); acc.y += __shfl_xor(acc.y, 32);
    acc.z += __shfl_xor(acc.z, 16); acc.z += __shfl_xor(acc.z, 32);
    acc.w += __shfl_xor(acc.w, 16); acc.w += __shfl_xor(acc.w, 32);

    float4 b1v  = *(const float4*)(b1 + 4 * cl);
    float4 wl2v = *(const float4*)(Wl2 + 4 * cl);
    float4 wr2v = *(const float4*)(Wr2 + 4 * cl);
    float inv_den = 1.f / den;
    float4 o;
    o.x = acc.x * inv_den + b1v.x;
    o.y = acc.y * inv_den + b1v.y;
    o.z = acc.z * inv_den + b1v.z;
    o.w = acc.w * inv_den + b1v.w;
    o.x = o.x > 0.f ? o.x : __expf(o.x) - 1.f;   // ELU
    o.y = o.y > 0.f ? o.y : __expf(o.y) - 1.f;
    o.z = o.z > 0.f ? o.z : __expf(o.z) - 1.f;
    o.w = o.w > 0.f ? o.w : __expf(o.w) - 1.f;
    float sl = o.x*wl2v.x + o.y*wl2v.y + o.z*wl2v.z + o.w*wl2v.w;
    float sr = o.x*wr2v.x + o.y*wr2v.y + o.z*wr2v.z + o.w*wr2v.w;
#pragma unroll
    for (int off = 1; off <= 8; off <<= 1) {
        sl += __shfl_xor(sl, off);
        sr += __shfl_xor(sr, off);
    }
    if (lane == 0) {
        xl2[node] = sl + bl2[0];
        xr2[node] = sr + br2[0];
    }
}

// fused layer-2: 16 lanes per node (4 nodes/wave), no-max softmax.
__global__ __launch_bounds__(256) void gat2_kernel(
        const uint2* __restrict__ row_info,
        const int* __restrict__ rec32, const float* __restrict__ att2,
        const float* __restrict__ xl2, const float* __restrict__ xr2,
        const float* __restrict__ b2, float* __restrict__ out) {
    int wave = threadIdx.x >> 6;
    int lane = threadIdx.x & 63;
    int sub  = lane >> 4;                 // node within wave
    int l    = lane & 15;
    int node = (blockIdx.x * 4 + wave) * 4 + sub;   // grid 6250 * 16 = 100000 exact
    uint2 ri = row_info[node];
    unsigned start = ri.x;
    unsigned cnt   = ri.y;
    float xrv = xr2[node];
    float a2  = att2[0];
    float den = 0.f, num = 0.f;
    for (unsigned idx = (unsigned)l; idx < cnt; idx += 16) {
        v2i r = __builtin_nontemporal_load((const v2i*)(rec32 + (size_t)(start + idx) * 8));
        float ee = __int_as_float(r.y);
        float xv = xl2[r.x];
        float v = xv + xrv + ee;
        v = fmaxf(v, NEG * v);
        float p = __expf(a2 * v);
        den += p;
        num += p * xv;
    }
#pragma unroll
    for (int off = 1; off <= 8; off <<= 1) {
        den += __shfl_xor(den, off);
        num += __shfl_xor(num, off);
    }
    if (l == 0) out[node] = num / den + b2[0];
}

extern "C" void kernel_launch(void* const* d_in, const int* in_sizes, int n_in,
                              void* d_out, int out_size, void* d_ws, size_t ws_size,
                              hipStream_t stream) {
    const float* x    = (const float*)d_in[0];
    const int*   ei   = (const int*)d_in[1];
    const float* ea   = (const float*)d_in[2];
    const float* Wl1  = (const float*)d_in[3];
    const float* bl1  = (const float*)d_in[4];
    const float* Wr1  = (const float*)d_in[5];
    const float* br1  = (const float*)d_in[6];
    const float* We1  = (const float*)d_in[7];
    const float* att1 = (const float*)d_in[8];
    const float* b1   = (const float*)d_in[9];
    const float* Wl2  = (const float*)d_in[10];
    const float* bl2  = (const float*)d_in[11];
    const float* Wr2  = (const float*)d_in[12];
    const float* br2  = (const float*)d_in[13];
    const float* We2  = (const float*)d_in[14];
    const float* att2 = (const float*)d_in[15];
    const float* b2   = (const float*)d_in[16];

    const int* src = ei;              // edge_index row 0
    const int* dst = ei + N_EDGES;    // edge_index row 1

    float* W = (float*)d_ws;
    size_t o = 0;
    float*    sum8      = W + o;               o += 8;
    float*    partials  = W + o;               o += MS_BLOCKS * 8;
    unsigned* deg       = (unsigned*)(W + o);  o += N_NODES;
    unsigned* local_inc = (unsigned*)(W + o);  o += N_NODES;
    unsigned* bsum      = (unsigned*)(W + o);  o += 128;
    unsigned* next      = (unsigned*)(W + o);  o += N_NODES;
    uint2*    row_info  = (uint2*)(W + o);     o += (size_t)N_NODES * 2;
    o = (o + 7) & ~(size_t)7;                  // 32B align
    int*      rec32     = (int*)(W + o);       o += (size_t)N_ITEMS * 8;      // 32B AoS
    __half*   xlh       = (__half*)(W + o);    o += (size_t)N_NODES * (HC/2); // fp16 xl
    __half*   xrh       = (__half*)(W + o);    o += (size_t)N_NODES * (HC/2); // fp16 xr
    float*    xl2       = W + o;               o += N_NODES;
    float*    xr2       = W + o;               o += N_NODES;

    hipMemsetAsync(deg, 0, (size_t)N_NODES * sizeof(unsigned), stream);
    mean_sum_kernel<<<MS_BLOCKS, 256, 0, stream>>>(ea, dst, partials, deg);
    scan1<<<SCAN_NB, SCAN_BS, 0, stream>>>(deg, local_inc, bsum, partials, sum8);
    scan23<<<(N_NODES + 255) / 256, 256, 0, stream>>>(local_inc, deg, bsum, next, row_info);
    scatter_kernel<<<(N_ITEMS + 255) / 256, 256, 0, stream>>>(
        src, dst, ea, sum8, We2, next, rec32);
    gemm1_kernel<<<N_NODES / 32, 256, 0, stream>>>(x, Wl1, bl1, Wr1, br1, xlh, xrh);
    gat1_kernel<<<(N_NODES + 3) / 4, 256, 0, stream>>>(
        row_info, rec32, We1, att1, b1, xlh, xrh,
        Wl2, bl2, Wr2, br2, xl2, xr2);
    gat2_kernel<<<N_NODES / 16, 256, 0, stream>>>(
        row_info, rec32, att2, xl2, xr2, b2, (float*)d_out);
}

// Round 19
// 364.897 us; speedup vs baseline: 1.1875x; 1.0737x over previous
//
#include <hip/hip_runtime.h>
#include <hip/hip_fp16.h>
#include <math.h>

#define N_NODES 100000
#define N_EDGES 1600000
#define N_ITEMS (N_EDGES + N_NODES)   // edges + self loops
#define F_IN 128
#define HC 64      // H*C (layer-1 output width)
#define NEG 0.2f
#define SCAN_BS 1024
#define SCAN_NB ((N_NODES + SCAN_BS - 1) / SCAN_BS)   // 98
#define MS_BLOCKS 1024

union H2I { __half2 h; int i; };
typedef int v2i __attribute__((ext_vector_type(2)));
typedef int v4i __attribute__((ext_vector_type(4)));
typedef _Float16 h2 __attribute__((ext_vector_type(2)));

#if __has_builtin(__builtin_amdgcn_fdot2)
__device__ __forceinline__ float DOT2(h2 a, h2 b, float c) {
    return __builtin_amdgcn_fdot2(a, b, c, false);
}
#else
__device__ __forceinline__ float DOT2(h2 a, h2 b, float c) {
    return c + (float)a.x * (float)b.x + (float)a.y * (float)b.y;
}
#endif

// packed fp16 max (header lacks __hmax2 on this ROCm)
__device__ __forceinline__ __half2 hmax2(__half2 a, __half2 b) {
    H2I ua, ub, uc; ua.h = a; ub.h = b;
    asm("v_pk_max_f16 %0, %1, %2" : "=v"(uc.i) : "v"(ua.i), "v"(ub.i));
    return uc.h;
}

// partial sums of edge_attr columns + degree histogram (deg pre-zeroed via memsetAsync)
__global__ void mean_sum_kernel(const float* __restrict__ ea, const int* __restrict__ dst,
                                float* __restrict__ partials, unsigned* __restrict__ deg) {
    __shared__ float sh[4][8];
    int stride = gridDim.x * blockDim.x;
    float acc[8] = {0.f,0.f,0.f,0.f,0.f,0.f,0.f,0.f};
    for (int r = blockIdx.x * blockDim.x + threadIdx.x; r < N_EDGES; r += stride) {
        const float4* p = (const float4*)(ea + (size_t)r * 8);
        float4 a = p[0], b = p[1];
        acc[0] += a.x; acc[1] += a.y; acc[2] += a.z; acc[3] += a.w;
        acc[4] += b.x; acc[5] += b.y; acc[6] += b.z; acc[7] += b.w;
        atomicAdd(&deg[dst[r]], 1u);
    }
    int wid  = threadIdx.x >> 6;
    int lane = threadIdx.x & 63;
#pragma unroll
    for (int k = 0; k < 8; k++) {
        float v = acc[k];
        for (int off = 32; off; off >>= 1) v += __shfl_down(v, off);
        if (lane == 0) sh[wid][k] = v;
    }
    __syncthreads();
    if (threadIdx.x < 8) {
        float s = sh[0][threadIdx.x] + sh[1][threadIdx.x] + sh[2][threadIdx.x] + sh[3][threadIdx.x];
        partials[blockIdx.x * 8 + threadIdx.x] = s;
    }
}

// inclusive block scan of (deg+1); block 0 additionally reduces partials -> sum8
__global__ void scan1(const unsigned* __restrict__ deg, unsigned* __restrict__ local_inc,
                      unsigned* __restrict__ bsum,
                      const float* __restrict__ partials, float* __restrict__ sum8) {
    if (blockIdx.x == 0 && threadIdx.x < 64) {
        int lane = threadIdx.x;
        int c = lane & 7, g = lane >> 3;
        float s = 0.f;
        for (int b = g; b < MS_BLOCKS; b += 8) s += partials[b * 8 + c];
        s += __shfl_xor(s, 8);
        s += __shfl_xor(s, 16);
        s += __shfl_xor(s, 32);
        if (lane < 8) sum8[lane] = s;
    }
    __shared__ unsigned wsum[16];
    int i = blockIdx.x * SCAN_BS + threadIdx.x;
    int lane = threadIdx.x & 63;
    int wid  = threadIdx.x >> 6;          // 0..15
    unsigned v = (i < N_NODES) ? (deg[i] + 1u) : 0u;   // +1 = self loop
    unsigned sc = v;
#pragma unroll
    for (int off = 1; off < 64; off <<= 1) {
        unsigned t = __shfl_up(sc, off);
        if (lane >= off) sc += t;
    }
    if (lane == 63) wsum[wid] = sc;
    __syncthreads();
    if (threadIdx.x < 16) {
        unsigned w = wsum[threadIdx.x];
#pragma unroll
        for (int off = 1; off < 16; off <<= 1) {
            unsigned t = __shfl_up(w, off);
            if ((int)threadIdx.x >= off) w += t;
        }
        wsum[threadIdx.x] = w;
    }
    __syncthreads();
    unsigned base = wid ? wsum[wid - 1] : 0u;
    sc += base;
    if (i < N_NODES) local_inc[i] = sc;
    if (threadIdx.x == SCAN_BS - 1) bsum[blockIdx.x] = sc;
}

// fused scan2+scan3: re-scan the 98 block sums, then emit next + row_info{start,cnt}
__global__ void scan23(const unsigned* __restrict__ local_inc, const unsigned* __restrict__ deg,
                       const unsigned* __restrict__ bsum,
                       unsigned* __restrict__ next, uint2* __restrict__ row_info) {
    __shared__ unsigned tmp[128];
    int t = threadIdx.x;
    if (t < 128) tmp[t] = (t < SCAN_NB) ? bsum[t] : 0u;
    __syncthreads();
    for (int off = 1; off < 128; off <<= 1) {
        unsigned add = 0u;
        if (t < 128 && t >= off) add = tmp[t - off];
        __syncthreads();
        if (t < 128) tmp[t] += add;
        __syncthreads();
    }
    int i = blockIdx.x * blockDim.x + t;
    if (i >= N_NODES) return;
    int b = i >> 10;                      // i / SCAN_BS
    unsigned base = b ? tmp[b - 1] : 0u;  // exclusive
    unsigned cnt = deg[i] + 1u;
    unsigned v = local_inc[i] - cnt + base;
    next[i] = v;
    row_info[i] = make_uint2(v, cnt);
}

// scatter edges (+ self loops) into destination-sorted 32B AoS records:
// rec32[pos] = {src, see2-bits, ea0..7 fp16} — one cache line per edge.
__global__ void scatter_kernel(const int* __restrict__ src, const int* __restrict__ dst,
                               const float* __restrict__ ea, const float* __restrict__ sum8,
                               const float* __restrict__ We2,
                               unsigned* __restrict__ next,
                               int* __restrict__ rec32) {
    int item = blockIdx.x * blockDim.x + threadIdx.x;
    if (item >= N_ITEMS) return;
    int s, d;
    float4 a, b;
    if (item < N_EDGES) {
        s = src[item]; d = dst[item];
        const float4* p = (const float4*)(ea + (size_t)item * 8);
        a = p[0]; b = p[1];
    } else {
        s = d = item - N_EDGES;
        const float inv = 1.0f / N_EDGES;
        a = make_float4(sum8[0]*inv, sum8[1]*inv, sum8[2]*inv, sum8[3]*inv);
        b = make_float4(sum8[4]*inv, sum8[5]*inv, sum8[6]*inv, sum8[7]*inv);
    }
    float ee2 = a.x*We2[0] + a.y*We2[1] + a.z*We2[2] + a.w*We2[3]
              + b.x*We2[4] + b.y*We2[5] + b.z*We2[6] + b.w*We2[7];
    unsigned pos = atomicAdd(&next[d], 1u);
    H2I e01, e23, e45, e67;
    e01.h = __floats2half2_rn(a.x, a.y);
    e23.h = __floats2half2_rn(a.z, a.w);
    e45.h = __floats2half2_rn(b.x, b.y);
    e67.h = __floats2half2_rn(b.z, b.w);
    int* base = rec32 + (size_t)pos * 8;
    v4i st1; st1.x = s; st1.y = __float_as_int(ee2); st1.z = e01.i; st1.w = e23.i;
    *(v4i*)base = st1;
    v2i st2; st2.x = e45.i; st2.y = e67.i;
    *(v2i*)(base + 4) = st2;
}

// xl = x@Wl + bl ; xr = x@Wr + br — fp16 output [node][64].
// W (both tables) staged in LDS as k-paired fp16 (32KB); x tile fp16 (9KB);
// inner loop = v_dot2_f32_f16 (fp16 mul, f32 accumulate). No global W re-reads.
__global__ __launch_bounds__(256) void gemm1_kernel(
        const float* __restrict__ x,
        const float* __restrict__ Wl, const float* __restrict__ bl,
        const float* __restrict__ Wr, const float* __restrict__ br,
        __half* __restrict__ xlh, __half* __restrict__ xrh) {
    __shared__ h2 W16[64][128];           // [kk][combined col] : (W[2kk][c], W[2kk+1][c])
    __shared__ h2 xs16[64][36];           // [kk][node] : (x[n][2kk], x[n][2kk+1]), padded
    int t = threadIdx.x & 31;             // combined col-quad: cols 4t..4t+3 (0..127)
    int g = threadIdx.x >> 5;             // node-quad: nodes 4g..4g+3
    int n0 = blockIdx.x * 32;             // N_NODES = 32*3125 exactly

    // stage W: 64 kk x 16 col-quads per table
    for (int i = threadIdx.x; i < 64 * 16; i += 256) {
        int kk = i >> 4, cq = i & 15;
        float4 w0 = *(const float4*)(Wl + (size_t)(2*kk)   * HC + 4*cq);
        float4 w1 = *(const float4*)(Wl + (size_t)(2*kk+1) * HC + 4*cq);
        h2 p;
        p.x = (_Float16)w0.x; p.y = (_Float16)w1.x; W16[kk][4*cq+0] = p;
        p.x = (_Float16)w0.y; p.y = (_Float16)w1.y; W16[kk][4*cq+1] = p;
        p.x = (_Float16)w0.z; p.y = (_Float16)w1.z; W16[kk][4*cq+2] = p;
        p.x = (_Float16)w0.w; p.y = (_Float16)w1.w; W16[kk][4*cq+3] = p;
        float4 v0 = *(const float4*)(Wr + (size_t)(2*kk)   * HC + 4*cq);
        float4 v1 = *(const float4*)(Wr + (size_t)(2*kk+1) * HC + 4*cq);
        p.x = (_Float16)v0.x; p.y = (_Float16)v1.x; W16[kk][64+4*cq+0] = p;
        p.x = (_Float16)v0.y; p.y = (_Float16)v1.y; W16[kk][64+4*cq+1] = p;
        p.x = (_Float16)v0.z; p.y = (_Float16)v1.z; W16[kk][64+4*cq+2] = p;
        p.x = (_Float16)v0.w; p.y = (_Float16)v1.w; W16[kk][64+4*cq+3] = p;
    }
    // stage x tile (32 nodes), k-paired fp16
    {
        int row = threadIdx.x >> 3;       // 0..31
        int cq  = threadIdx.x & 7;
#pragma unroll
        for (int r = 0; r < 4; r++) {
            int c = cq * 4 + r * 32;      // multiple of 4 -> even
            float4 v = *(const float4*)(x + (size_t)(n0 + row) * F_IN + c);
            h2 p;
            p.x = (_Float16)v.x; p.y = (_Float16)v.y; xs16[c/2][row]     = p;
            p.x = (_Float16)v.z; p.y = (_Float16)v.w; xs16[c/2 + 1][row] = p;
        }
    }
    __syncthreads();

    const float* bsel = (t < 16) ? bl : br;
    int jc = (t < 16) ? 4 * t : 4 * t - HC;
    float4 bias = *(const float4*)(bsel + jc);
    __half* table = (t < 16) ? xlh : xrh;
    int nb = g * 4;

    float4 a0 = bias, a1 = bias, a2 = bias, a3 = bias;
#pragma unroll 4
    for (int kk = 0; kk < 64; kk++) {
        h2 w0 = W16[kk][4*t+0], w1 = W16[kk][4*t+1], w2 = W16[kk][4*t+2], w3 = W16[kk][4*t+3];
        h2 x0 = xs16[kk][nb+0], x1 = xs16[kk][nb+1], x2 = xs16[kk][nb+2], x3 = xs16[kk][nb+3];
        a0.x = DOT2(x0, w0, a0.x); a0.y = DOT2(x0, w1, a0.y); a0.z = DOT2(x0, w2, a0.z); a0.w = DOT2(x0, w3, a0.w);
        a1.x = DOT2(x1, w0, a1.x); a1.y = DOT2(x1, w1, a1.y); a1.z = DOT2(x1, w2, a1.z); a1.w = DOT2(x1, w3, a1.w);
        a2.x = DOT2(x2, w0, a2.x); a2.y = DOT2(x2, w1, a2.y); a2.z = DOT2(x2, w2, a2.z); a2.w = DOT2(x2, w3, a2.w);
        a3.x = DOT2(x3, w0, a3.x); a3.y = DOT2(x3, w1, a3.y); a3.z = DOT2(x3, w2, a3.z); a3.w = DOT2(x3, w3, a3.w);
    }
    float4 arr[4] = {a0, a1, a2, a3};
#pragma unroll
    for (int r = 0; r < 4; r++) {
        H2I u0, u1;
        u0.h = __floats2half2_rn(arr[r].x, arr[r].y);
        u1.h = __floats2half2_rn(arr[r].z, arr[r].w);
        *(int2*)(table + (size_t)(n0 + nb + r) * HC + jc) = make_int2(u0.i, u1.i);
    }
}

// packed-fp16 edge update (no-max softmax; self loop guarantees den > 0)
__device__ __forceinline__ void edge_update_h(const __half2* __restrict__ weA,
                                              const __half2* __restrict__ weB,
                                              __half2 attA, __half2 attB,
                                              __half2 xr2a, __half2 xr2b,
                                              bool valid, v4i L1, v2i L2, v2i xp,
                                              float& den, float4& acc) {
    H2I ea01, ea23, ea45, ea67, xl01, xl23;
    ea01.i = L1.z; ea23.i = L1.w; ea45.i = L2.x; ea67.i = L2.y;
    xl01.i = xp.x; xl23.i = xp.y;
    __half2 va = __hadd2(xl01.h, xr2a);
    __half2 vb = __hadd2(xl23.h, xr2b);
    __half2 e;
    e = __low2half2(ea01.h);  va = __hfma2(e, weA[0], va); vb = __hfma2(e, weB[0], vb);
    e = __high2half2(ea01.h); va = __hfma2(e, weA[1], va); vb = __hfma2(e, weB[1], vb);
    e = __low2half2(ea23.h);  va = __hfma2(e, weA[2], va); vb = __hfma2(e, weB[2], vb);
    e = __high2half2(ea23.h); va = __hfma2(e, weA[3], va); vb = __hfma2(e, weB[3], vb);
    e = __low2half2(ea45.h);  va = __hfma2(e, weA[4], va); vb = __hfma2(e, weB[4], vb);
    e = __high2half2(ea45.h); va = __hfma2(e, weA[5], va); vb = __hfma2(e, weB[5], vb);
    e = __low2half2(ea67.h);  va = __hfma2(e, weA[6], va); vb = __hfma2(e, weB[6], vb);
    e = __high2half2(ea67.h); va = __hfma2(e, weA[7], va); vb = __hfma2(e, weB[7], vb);
    const __half2 k02 = __float2half2_rn(NEG);
    va = hmax2(va, __hmul2(va, k02));        // leakyrelu
    vb = hmax2(vb, __hmul2(vb, k02));
    __half2 pd = __hfma2(vb, attB, __hmul2(va, attA));
    float2 pf = __half22float2(pd);
    float prod = pf.x + pf.y;
    prod += __shfl_xor(prod, 1);
    prod += __shfl_xor(prod, 2);             // per-head logit in each 4-lane cluster
    float p = valid ? __expf(prod) : 0.f;
    float2 xa = __half22float2(xl01.h), xb = __half22float2(xl23.h);
    den   += p;
    acc.x += p * xa.x;
    acc.y += p * xa.y;
    acc.z += p * xb.x;
    acc.w += p * xb.y;
}

// fused layer-1: ONE WAVE PER WORKGROUP (64 threads) — each node's wave retires
// independently, no intra-block tail imbalance. 8 edges/iter as two streams,
// depth-1 prefetch. fp16 packed math, no-max softmax. Epilogue fused.
__global__ __launch_bounds__(64) void gat1_kernel(
                            const uint2* __restrict__ row_info,
                            const int* __restrict__ rec32,
                            const float* __restrict__ We1, const float* __restrict__ att1,
                            const float* __restrict__ b1,
                            const __half* __restrict__ xlh, const __half* __restrict__ xrh,
                            const float* __restrict__ Wl2, const float* __restrict__ bl2,
                            const float* __restrict__ Wr2, const float* __restrict__ br2,
                            float* __restrict__ xl2, float* __restrict__ xr2) {
    int node = blockIdx.x;                // grid = N_NODES
    int lane = threadIdx.x;               // 0..63
    int g  = lane >> 4;          // edge sub-stream 0..3
    int cl = lane & 15;          // channel-slot: channels 4cl..4cl+3
    uint2 ri = row_info[node];
    unsigned start = ri.x;
    unsigned cnt   = ri.y;
    unsigned cm1   = cnt - 1u;

    __half2 weA[8], weB[8];
#pragma unroll
    for (int k = 0; k < 8; k++) {
        float4 w = *(const float4*)(We1 + k * HC + 4 * cl);
        weA[k] = __floats2half2_rn(w.x, w.y);
        weB[k] = __floats2half2_rn(w.z, w.w);
    }
    float4 at = *(const float4*)(att1 + 4 * cl);
    __half2 attA = __floats2half2_rn(at.x, at.y);
    __half2 attB = __floats2half2_rn(at.z, at.w);
    v2i xrp = *(const v2i*)(xrh + (size_t)node * HC + 4 * cl);
    H2I xru0, xru1; xru0.i = xrp.x; xru1.i = xrp.y;
    __half2 xr2a = xru0.h, xr2b = xru1.h;

    float denA = 0.f, denB = 0.f;
    float4 accA = make_float4(0.f,0.f,0.f,0.f), accB = make_float4(0.f,0.f,0.f,0.f);

#define IDXA(J) (start + min((J) + (unsigned)g, cm1))
#define IDXB(J) (start + min((J) + 4u + (unsigned)g, cm1))
    // prologue: depth-1 prefetch, two streams
    unsigned iA = IDXA(0u), iB = IDXB(0u);
    v4i L1A = __builtin_nontemporal_load((const v4i*)(rec32 + (size_t)iA * 8));
    v4i L1B = __builtin_nontemporal_load((const v4i*)(rec32 + (size_t)iB * 8));
    v2i L2A = __builtin_nontemporal_load((const v2i*)(rec32 + (size_t)iA * 8 + 4));
    v2i L2B = __builtin_nontemporal_load((const v2i*)(rec32 + (size_t)iB * 8 + 4));
    v2i xpA = *(const v2i*)(xlh + (size_t)L1A.x * HC + 4 * cl);
    v2i xpB = *(const v2i*)(xlh + (size_t)L1B.x * HC + 4 * cl);

    for (unsigned j = 0; j < cnt; j += 8) {
        v4i c1A = L1A, c1B = L1B;
        v2i c2A = L2A, c2B = L2B, cxA = xpA, cxB = xpB;
        bool vA = (j + g) < cnt, vB = (j + 4 + g) < cnt;
        if (j + 8 < cnt) {
            iA = IDXA(j + 8); iB = IDXB(j + 8);
            L1A = __builtin_nontemporal_load((const v4i*)(rec32 + (size_t)iA * 8));
            L1B = __builtin_nontemporal_load((const v4i*)(rec32 + (size_t)iB * 8));
            L2A = __builtin_nontemporal_load((const v2i*)(rec32 + (size_t)iA * 8 + 4));
            L2B = __builtin_nontemporal_load((const v2i*)(rec32 + (size_t)iB * 8 + 4));
            xpA = *(const v2i*)(xlh + (size_t)L1A.x * HC + 4 * cl);
            xpB = *(const v2i*)(xlh + (size_t)L1B.x * HC + 4 * cl);
        }
        edge_update_h(weA, weB, attA, attB, xr2a, xr2b, vA, c1A, c2A, cxA, denA, accA);
        edge_update_h(weA, weB, attA, attB, xr2a, xr2b, vB, c1B, c2B, cxB, denB, accB);
    }
#undef IDXA
#undef IDXB

    float den = denA + denB;
    float4 acc;
    acc.x = accA.x + accB.x;
    acc.y = accA.y + accB.y;
    acc.z = accA.z + accB.z;
    acc.w = accA.w + accB.w;

    // merge the 4 g-streams (lanes differing in bits 4,5) — plain sums
    den   += __shfl_xor(den, 16);   den   += __shfl_xor(den, 32);
    acc.x += __shfl_xor(acc.x, 16); acc.x += __shfl_xor(acc.x, 32);
    acc.y += __shfl_xor(acc.y, 16); acc.y += __shfl_xor(acc.y, 32);
    acc.z += __shfl_xor(acc.z, 16); acc.z += __shfl_xor(acc.z, 32);
    acc.w += __shfl_xor(acc.w, 16); acc.w += __shfl_xor(acc.w, 32);

    float4 b1v  = *(const float4*)(b1 + 4 * cl);
    float4 wl2v = *(const float4*)(Wl2 + 4 * cl);
    float4 wr2v = *(const float4*)(Wr2 + 4 * cl);
    float inv_den = 1.f / den;
    float4 o;
    o.x = acc.x * inv_den + b1v.x;
    o.y = acc.y * inv_den + b1v.y;
    o.z = acc.z * inv_den + b1v.z;
    o.w = acc.w * inv_den + b1v.w;
    o.x = o.x > 0.f ? o.x : __expf(o.x) - 1.f;   // ELU
    o.y = o.y > 0.f ? o.y : __expf(o.y) - 1.f;
    o.z = o.z > 0.f ? o.z : __expf(o.z) - 1.f;
    o.w = o.w > 0.f ? o.w : __expf(o.w) - 1.f;
    float sl = o.x*wl2v.x + o.y*wl2v.y + o.z*wl2v.z + o.w*wl2v.w;
    float sr = o.x*wr2v.x + o.y*wr2v.y + o.z*wr2v.z + o.w*wr2v.w;
#pragma unroll
    for (int off = 1; off <= 8; off <<= 1) {
        sl += __shfl_xor(sl, off);
        sr += __shfl_xor(sr, off);
    }
    if (lane == 0) {
        xl2[node] = sl + bl2[0];
        xr2[node] = sr + br2[0];
    }
}

// fused layer-2: one wave per workgroup, 16 lanes per node (4 nodes/wave).
__global__ __launch_bounds__(64) void gat2_kernel(
        const uint2* __restrict__ row_info,
        const int* __restrict__ rec32, const float* __restrict__ att2,
        const float* __restrict__ xl2, const float* __restrict__ xr2,
        const float* __restrict__ b2, float* __restrict__ out) {
    int lane = threadIdx.x;
    int sub  = lane >> 4;                 // node within wave
    int l    = lane & 15;
    int node = blockIdx.x * 4 + sub;      // grid = N_NODES/4 = 25000
    uint2 ri = row_info[node];
    unsigned start = ri.x;
    unsigned cnt   = ri.y;
    float xrv = xr2[node];
    float a2  = att2[0];
    float den = 0.f, num = 0.f;
    for (unsigned idx = (unsigned)l; idx < cnt; idx += 16) {
        v2i r = __builtin_nontemporal_load((const v2i*)(rec32 + (size_t)(start + idx) * 8));
        float ee = __int_as_float(r.y);
        float xv = xl2[r.x];
        float v = xv + xrv + ee;
        v = fmaxf(v, NEG * v);
        float p = __expf(a2 * v);
        den += p;
        num += p * xv;
    }
#pragma unroll
    for (int off = 1; off <= 8; off <<= 1) {
        den += __shfl_xor(den, off);
        num += __shfl_xor(num, off);
    }
    if (l == 0) out[node] = num / den + b2[0];
}

extern "C" void kernel_launch(void* const* d_in, const int* in_sizes, int n_in,
                              void* d_out, int out_size, void* d_ws, size_t ws_size,
                              hipStream_t stream) {
    const float* x    = (const float*)d_in[0];
    const int*   ei   = (const int*)d_in[1];
    const float* ea   = (const float*)d_in[2];
    const float* Wl1  = (const float*)d_in[3];
    const float* bl1  = (const float*)d_in[4];
    const float* Wr1  = (const float*)d_in[5];
    const float* br1  = (const float*)d_in[6];
    const float* We1  = (const float*)d_in[7];
    const float* att1 = (const float*)d_in[8];
    const float* b1   = (const float*)d_in[9];
    const float* Wl2  = (const float*)d_in[10];
    const float* bl2  = (const float*)d_in[11];
    const float* Wr2  = (const float*)d_in[12];
    const float* br2  = (const float*)d_in[13];
    const float* We2  = (const float*)d_in[14];
    const float* att2 = (const float*)d_in[15];
    const float* b2   = (const float*)d_in[16];

    const int* src = ei;              // edge_index row 0
    const int* dst = ei + N_EDGES;    // edge_index row 1

    float* W = (float*)d_ws;
    size_t o = 0;
    float*    sum8      = W + o;               o += 8;
    float*    partials  = W + o;               o += MS_BLOCKS * 8;
    unsigned* deg       = (unsigned*)(W + o);  o += N_NODES;
    unsigned* local_inc = (unsigned*)(W + o);  o += N_NODES;
    unsigned* bsum      = (unsigned*)(W + o);  o += 128;
    unsigned* next      = (unsigned*)(W + o);  o += N_NODES;
    uint2*    row_info  = (uint2*)(W + o);     o += (size_t)N_NODES * 2;
    o = (o + 7) & ~(size_t)7;                  // 32B align
    int*      rec32     = (int*)(W + o);       o += (size_t)N_ITEMS * 8;      // 32B AoS
    __half*   xlh       = (__half*)(W + o);    o += (size_t)N_NODES * (HC/2); // fp16 xl
    __half*   xrh       = (__half*)(W + o);    o += (size_t)N_NODES * (HC/2); // fp16 xr
    float*    xl2       = W + o;               o += N_NODES;
    float*    xr2       = W + o;               o += N_NODES;

    hipMemsetAsync(deg, 0, (size_t)N_NODES * sizeof(unsigned), stream);
    mean_sum_kernel<<<MS_BLOCKS, 256, 0, stream>>>(ea, dst, partials, deg);
    scan1<<<SCAN_NB, SCAN_BS, 0, stream>>>(deg, local_inc, bsum, partials, sum8);
    scan23<<<(N_NODES + 255) / 256, 256, 0, stream>>>(local_inc, deg, bsum, next, row_info);
    scatter_kernel<<<(N_ITEMS + 255) / 256, 256, 0, stream>>>(
        src, dst, ea, sum8, We2, next, rec32);
    gemm1_kernel<<<N_NODES / 32, 256, 0, stream>>>(x, Wl1, bl1, Wr1, br1, xlh, xrh);
    gat1_kernel<<<N_NODES, 64, 0, stream>>>(
        row_info, rec32, We1, att1, b1, xlh, xrh,
        Wl2, bl2, Wr2, br2, xl2, xr2);
    gat2_kernel<<<N_NODES / 4, 64, 0, stream>>>(
        row_info, rec32, att2, xl2, xr2, b2, (float*)d_out);
}